// Round 7
// baseline (142.465 us; speedup 1.0000x reference)
//
#include <hip/hip_runtime.h>
#include <hip/hip_bf16.h>

// B=32, N=64, D=128, H=256
typedef __attribute__((ext_vector_type(8))) _Float16 half8;
typedef __attribute__((ext_vector_type(4))) float f32x4;

// ---------------------------------------------------------------------------
// Prep: blocks 0..255  : L/R = objects @ gW1(top/bottom), 8 rows each.
//         Lh = fp16(L + gb1)  [row][k] linear
//         Rh = fp16(R)        [row][k] linear (no swizzle: main reads global)
//       blocks 256..271: transpose gW2 -> W2h[col][k] fp16
//       block  272     : zero S; dvec = 4032*(gb3@fW1) + fb1 (4-way j-split)
//       blocks 273..304: M = gW3 @ fW1, 8 rows each (4-way j-split, f32x4)
// ---------------------------------------------------------------------------
__global__ __launch_bounds__(256) void rn_prep(
    const float* __restrict__ obj, const float* __restrict__ gW1,
    const float* __restrict__ gb1, const float* __restrict__ gW2,
    const float* __restrict__ gW3, const float* __restrict__ gb3,
    const float* __restrict__ fW1, const float* __restrict__ fb1,
    _Float16* __restrict__ Lh, _Float16* __restrict__ Rh,
    _Float16* __restrict__ W2h, float* __restrict__ S,
    float* __restrict__ M, float* __restrict__ dvec)
{
    __shared__ float so[8 * 128];
    __shared__ float tt[64 * 65];
    __shared__ float sg[8 * 256];
    __shared__ float ps[4][8][256];
    const int blk = blockIdx.x, t = threadIdx.x;

    if (blk < 256) {
        const int r0 = blk * 8;
        #pragma unroll
        for (int it = 0; it < 4; ++it) so[it * 256 + t] = obj[r0 * 128 + it * 256 + t];
        __syncthreads();
        float accL[8], accR[8];
        #pragma unroll
        for (int r = 0; r < 8; ++r) { accL[r] = 0.f; accR[r] = 0.f; }
        for (int k = 0; k < 128; ++k) {
            float wL = gW1[k * 256 + t];
            float wR = gW1[(128 + k) * 256 + t];
            #pragma unroll
            for (int r = 0; r < 8; ++r) {
                float o = so[r * 128 + k];
                accL[r] += o * wL;
                accR[r] += o * wR;
            }
        }
        float bb = gb1[t];
        #pragma unroll
        for (int r = 0; r < 8; ++r) {
            int row = r0 + r;
            Lh[row * 256 + t] = (_Float16)(accL[r] + bb);
            Rh[row * 256 + t] = (_Float16)accR[r];
        }
    } else if (blk < 272) {
        const int tb = blk - 256;
        const int k0 = (tb >> 2) * 64, c0 = (tb & 3) * 64;
        for (int it = 0; it < 16; ++it) {
            int idx = it * 256 + t, rr = idx >> 6, cc = idx & 63;
            tt[rr * 65 + cc] = gW2[(k0 + rr) * 256 + c0 + cc];
        }
        __syncthreads();
        for (int it = 0; it < 16; ++it) {
            int idx = it * 256 + t, cr = idx >> 6, kk = idx & 63;
            W2h[(c0 + cr) * 256 + (k0 + kk)] = (_Float16)tt[kk * 65 + cr];
        }
    } else if (blk == 272) {
        for (int it = 0; it < 32; ++it) S[it * 256 + t] = 0.f;
        const int cg = t & 63, jq = t >> 6, c0 = cg * 4;
        f32x4 a = (f32x4){0.f, 0.f, 0.f, 0.f};
        #pragma unroll 8
        for (int jj = 0; jj < 64; ++jj) {
            int j = jq * 64 + jj;
            a += gb3[j] * (*(const f32x4*)&fW1[j * 256 + c0]);
        }
        *(f32x4*)&ps[jq][0][c0] = a;
        __syncthreads();
        float s = ps[0][0][t] + ps[1][0][t] + ps[2][0][t] + ps[3][0][t];
        dvec[t] = 4032.0f * s + fb1[t];
    } else {
        const int r0 = (blk - 273) * 8;
        const int cg = t & 63, jq = t >> 6, c0 = cg * 4;
        #pragma unroll
        for (int it = 0; it < 8; ++it) sg[it * 256 + t] = gW3[(r0 + it) * 256 + t];
        __syncthreads();
        f32x4 acc[8];
        #pragma unroll
        for (int r = 0; r < 8; ++r) acc[r] = (f32x4){0.f, 0.f, 0.f, 0.f};
        #pragma unroll 8
        for (int jj = 0; jj < 64; ++jj) {
            int j = jq * 64 + jj;
            f32x4 wv = *(const f32x4*)&fW1[j * 256 + c0];
            #pragma unroll
            for (int r = 0; r < 8; ++r) acc[r] += sg[r * 256 + j] * wv;
        }
        #pragma unroll
        for (int r = 0; r < 8; ++r) *(f32x4*)&ps[jq][r][c0] = acc[r];
        __syncthreads();
        #pragma unroll
        for (int r = 0; r < 8; ++r)
            M[(r0 + r) * 256 + t] = ps[0][r][t] + ps[1][r][t] + ps[2][r][t] + ps[3][r][t];
    }
}

// ---------------------------------------------------------------------------
// Main (NO LDS, NO BARRIERS): grid 256 = 32 b x 8 ig; 512 thr = 8 waves =
// (mg 2) x (ng 4). Wave (mg,ng): rows [mg*32,+32), cols [ng*64,+64); 8 i's.
// All operands from global: bfr (W2h slice, register-resident), rh (Rh rows,
// register-resident, ii-invariant), lhv (Lh row, 4 distinct 16B/wave, L1).
// A-frag: pk_max(pk_add(lh,rh),0); mfma_f32_16x16x32_f16. Epilogue: f32x4
// relu+sum, diagonal removed by one compare+subtract. One atomicAdd per col.
// ---------------------------------------------------------------------------
__global__ __launch_bounds__(512, 2) void rn_main(
    const _Float16* __restrict__ Lh, const _Float16* __restrict__ Rh,
    const _Float16* __restrict__ W2h, const float* __restrict__ gb2,
    float* __restrict__ S)
{
    const int blk = blockIdx.x;               // 256 = 32 b x 8 ig
    const int b = blk >> 3, ig = blk & 7;
    const int t = threadIdx.x, lane = t & 63, w = t >> 6;
    const int mg = w >> 2, ng = w & 3;
    const int lc = lane & 15, lg = lane >> 4;

    // register-resident B: 4 n-tiles x 8 ks (128 VGPR), from L2-hot W2h
    half8 bfr[4][8];
    #pragma unroll
    for (int n = 0; n < 4; ++n)
        #pragma unroll
        for (int ks = 0; ks < 8; ++ks)
            bfr[n][ks] = *(const half8*)(W2h + (ng * 64 + n * 16 + lc) * 256 + ks * 32 + lg * 8);

    // register-resident Rh rows: 2 m-tiles x 8 ks (64 VGPR), ii-invariant
    half8 rh[2][8];
    #pragma unroll
    for (int m2 = 0; m2 < 2; ++m2) {
        int row = b * 64 + mg * 32 + m2 * 16 + lc;
        #pragma unroll
        for (int ks = 0; ks < 8; ++ks)
            rh[m2][ks] = *(const half8*)(Rh + row * 256 + ks * 32 + lg * 8);
    }

    float bias[4];
    #pragma unroll
    for (int n = 0; n < 4; ++n) bias[n] = gb2[ng * 64 + n * 16 + lc];

    const _Float16* lbase = Lh + (b * 64 + ig * 8) * 256;
    const half8 zero8 = {(_Float16)0.f, (_Float16)0.f, (_Float16)0.f, (_Float16)0.f,
                         (_Float16)0.f, (_Float16)0.f, (_Float16)0.f, (_Float16)0.f};
    const f32x4 zero4 = (f32x4){0.f, 0.f, 0.f, 0.f};
    float csum[4] = {0.f, 0.f, 0.f, 0.f};
    const int rgbase = mg * 32 + lg * 4;      // this thread's 4-row group base (per m2: +m2*16)

    #pragma unroll
    for (int ii = 0; ii < 8; ++ii) {
        f32x4 acc[2][4];
        #pragma unroll
        for (int m2 = 0; m2 < 2; ++m2)
            #pragma unroll
            for (int n = 0; n < 4; ++n)
                acc[m2][n] = zero4;

        #pragma unroll
        for (int ks = 0; ks < 8; ++ks) {
            half8 lhv = *(const half8*)(lbase + ii * 256 + ks * 32 + lg * 8);
            #pragma unroll
            for (int m2 = 0; m2 < 2; ++m2) {
                half8 av = __builtin_elementwise_max(lhv + rh[m2][ks], zero8);
                #pragma unroll
                for (int n = 0; n < 4; ++n)
                    acc[m2][n] = __builtin_amdgcn_mfma_f32_16x16x32_f16(
                        av, bfr[n][ks], acc[m2][n], 0, 0, 0);
            }
        }

        const int iglob = ig * 8 + ii;        // iglob&3 == ii&3 (compile-time)
        #pragma unroll
        for (int n = 0; n < 4; ++n) {
            f32x4 bv = (f32x4){bias[n], bias[n], bias[n], bias[n]};
            #pragma unroll
            for (int m2 = 0; m2 < 2; ++m2) {
                f32x4 v = __builtin_elementwise_max(acc[m2][n] + bv, zero4);
                float cs = (v[0] + v[1]) + (v[2] + v[3]);
                if (rgbase + m2 * 16 == (iglob & ~3))   // diag row in this group
                    cs -= v[ii & 3];
                csum[n] += cs;
            }
        }
    }

    #pragma unroll
    for (int n = 0; n < 4; ++n) {
        float cs = csum[n];
        cs += __shfl_xor(cs, 16);
        cs += __shfl_xor(cs, 32);
        if (lane < 16) atomicAdd(&S[b * 256 + ng * 64 + n * 16 + lc], cs);
    }
}

// ---------------------------------------------------------------------------
// Final (2 phases): block per b, 1024 thr = (64 col-groups of 4) x (16 kq).
//   u   = relu(S[b] @ M + d);  out = u @ fW2 + fb2
// fW2 fragments prefetched into regs during phase A.
// ---------------------------------------------------------------------------
__global__ __launch_bounds__(1024) void rn_final(
    const float* __restrict__ S, const float* __restrict__ M,
    const float* __restrict__ dvec, const float* __restrict__ fW2,
    const float* __restrict__ fb2, float* __restrict__ out)
{
    __shared__ float vec[256];
    __shared__ float ps[16][260];
    const int b = blockIdx.x, t = threadIdx.x;
    const int cg = t & 63, kq = t >> 6;
    const int c0 = cg * 4;

    if (t < 256) vec[t] = S[b * 256 + t];
    __syncthreads();

    f32x4 w2r[16];
    {
        f32x4 s = (f32x4){0.f, 0.f, 0.f, 0.f};
        #pragma unroll
        for (int kk = 0; kk < 16; ++kk) {
            int k = kq * 16 + kk;
            s += (*(const f32x4*)&M[k * 256 + c0]) * vec[k];
        }
        *(f32x4*)&ps[kq][c0] = s;
        #pragma unroll
        for (int kk = 0; kk < 16; ++kk)
            w2r[kk] = *(const f32x4*)&fW2[(kq * 16 + kk) * 256 + c0];
    }
    __syncthreads();
    if (t < 256) {
        float a = 0.f;
        #pragma unroll
        for (int q = 0; q < 16; ++q) a += ps[q][t];
        vec[t] = fmaxf(a + dvec[t], 0.f);
    }
    __syncthreads();

    {
        f32x4 s = (f32x4){0.f, 0.f, 0.f, 0.f};
        #pragma unroll
        for (int kk = 0; kk < 16; ++kk)
            s += w2r[kk] * vec[kq * 16 + kk];
        *(f32x4*)&ps[kq][c0] = s;
    }
    __syncthreads();
    if (t < 256) {
        float a = 0.f;
        #pragma unroll
        for (int q = 0; q < 16; ++q) a += ps[q][t];
        out[b * 256 + t] = a + fb2[t];
    }
}

extern "C" void kernel_launch(void* const* d_in, const int* in_sizes, int n_in,
                              void* d_out, int out_size, void* d_ws, size_t ws_size,
                              hipStream_t stream)
{
    const float* obj = (const float*)d_in[0];
    const float* gW1 = (const float*)d_in[1];
    const float* gb1 = (const float*)d_in[2];
    const float* gW2 = (const float*)d_in[3];
    const float* gb2 = (const float*)d_in[4];
    const float* gW3 = (const float*)d_in[5];
    const float* gb3 = (const float*)d_in[6];
    const float* fW1 = (const float*)d_in[7];
    const float* fb1 = (const float*)d_in[8];
    const float* fW2 = (const float*)d_in[9];
    const float* fb2 = (const float*)d_in[10];
    float* out = (float*)d_out;

    char* ws = (char*)d_ws;
    _Float16* Lh  = (_Float16*)(ws);                           // 1 MB
    _Float16* Rh  = (_Float16*)(ws + (1u << 20));              // 1 MB (linear fp16)
    _Float16* W2h = (_Float16*)(ws + (2u << 20));              // 128 KB
    float*    S   = (float*)(ws + (2u << 20) + (128u << 10));  // 32 KB
    float*    M   = (float*)(ws + (2u << 20) + (160u << 10));  // 256 KB
    float*    dv  = (float*)(ws + (2u << 20) + (416u << 10));  // 1 KB

    rn_prep <<<305, 256, 0, stream>>>(obj, gW1, gb1, gW2, gW3, gb3, fW1, fb1,
                                      Lh, Rh, W2h, S, M, dv);
    rn_main <<<256, 512, 0, stream>>>(Lh, Rh, W2h, gb2, S);
    rn_final<<<32, 1024, 0, stream>>>(S, M, dv, fW2, fb2, out);
}

// Round 8
// 52.696 us; speedup vs baseline: 2.7036x; 2.7036x over previous
//
#include <hip/hip_runtime.h>
#include <hip/hip_bf16.h>

// B=32, N=64, D=128, H=256
typedef __attribute__((ext_vector_type(8))) _Float16 half8;
typedef __attribute__((ext_vector_type(4))) float f32x4;

// ---------------------------------------------------------------------------
// Prep: blocks 0..255  : L/R = objects @ gW1(top/bottom), 8 rows each.
//         Lh = fp16(L + gb1)  [row][k] linear
//         Rh = fp16(R)        [row][k] linear
//       blocks 256..271: transpose gW2 -> W2h[col][k] fp16
//       block  272     : zero S; dvec = 4032*(gb3@fW1) + fb1
//       blocks 273..304: M = gW3 @ fW1, 8 rows each (4-way j-split)
// LDS overlaid via union (40KB) so every role keeps high occupancy.
// ---------------------------------------------------------------------------
union PrepShared {
    struct { float so[8 * 128]; float tt[64 * 65]; } a;
    struct { float sg[8 * 256]; float ps[4][8][256]; } m;
};

__global__ __launch_bounds__(256) void rn_prep(
    const float* __restrict__ obj, const float* __restrict__ gW1,
    const float* __restrict__ gb1, const float* __restrict__ gW2,
    const float* __restrict__ gW3, const float* __restrict__ gb3,
    const float* __restrict__ fW1, const float* __restrict__ fb1,
    _Float16* __restrict__ Lh, _Float16* __restrict__ Rh,
    _Float16* __restrict__ W2h, float* __restrict__ S,
    float* __restrict__ M, float* __restrict__ dvec)
{
    __shared__ PrepShared sh;
    const int blk = blockIdx.x, t = threadIdx.x;

    if (blk < 256) {
        float* so = sh.a.so;
        const int r0 = blk * 8;
        #pragma unroll
        for (int it = 0; it < 4; ++it) so[it * 256 + t] = obj[r0 * 128 + it * 256 + t];
        __syncthreads();
        float accL[8], accR[8];
        #pragma unroll
        for (int r = 0; r < 8; ++r) { accL[r] = 0.f; accR[r] = 0.f; }
        for (int k = 0; k < 128; ++k) {
            float wL = gW1[k * 256 + t];
            float wR = gW1[(128 + k) * 256 + t];
            #pragma unroll
            for (int r = 0; r < 8; ++r) {
                float o = so[r * 128 + k];
                accL[r] += o * wL;
                accR[r] += o * wR;
            }
        }
        float bb = gb1[t];
        #pragma unroll
        for (int r = 0; r < 8; ++r) {
            int row = r0 + r;
            Lh[row * 256 + t] = (_Float16)(accL[r] + bb);
            Rh[row * 256 + t] = (_Float16)accR[r];
        }
    } else if (blk < 272) {
        float* tt = sh.a.tt;
        const int tb = blk - 256;
        const int k0 = (tb >> 2) * 64, c0 = (tb & 3) * 64;
        for (int it = 0; it < 16; ++it) {
            int idx = it * 256 + t, rr = idx >> 6, cc = idx & 63;
            tt[rr * 65 + cc] = gW2[(k0 + rr) * 256 + c0 + cc];
        }
        __syncthreads();
        for (int it = 0; it < 16; ++it) {
            int idx = it * 256 + t, cr = idx >> 6, kk = idx & 63;
            W2h[(c0 + cr) * 256 + (k0 + kk)] = (_Float16)tt[kk * 65 + cr];
        }
    } else if (blk == 272) {
        for (int it = 0; it < 32; ++it) S[it * 256 + t] = 0.f;
        const int cg = t & 63, jq = t >> 6, c0 = cg * 4;
        f32x4 a = (f32x4){0.f, 0.f, 0.f, 0.f};
        #pragma unroll 8
        for (int jj = 0; jj < 64; ++jj) {
            int j = jq * 64 + jj;
            a += gb3[j] * (*(const f32x4*)&fW1[j * 256 + c0]);
        }
        *(f32x4*)&sh.m.ps[jq][0][c0] = a;
        __syncthreads();
        float s = sh.m.ps[0][0][t] + sh.m.ps[1][0][t] + sh.m.ps[2][0][t] + sh.m.ps[3][0][t];
        dvec[t] = 4032.0f * s + fb1[t];
    } else {
        float* sg = sh.m.sg;
        const int r0 = (blk - 273) * 8;
        const int cg = t & 63, jq = t >> 6, c0 = cg * 4;
        #pragma unroll
        for (int it = 0; it < 8; ++it) sg[it * 256 + t] = gW3[(r0 + it) * 256 + t];
        __syncthreads();
        f32x4 acc[8];
        #pragma unroll
        for (int r = 0; r < 8; ++r) acc[r] = (f32x4){0.f, 0.f, 0.f, 0.f};
        #pragma unroll 8
        for (int jj = 0; jj < 64; ++jj) {
            int j = jq * 64 + jj;
            f32x4 wv = *(const f32x4*)&fW1[j * 256 + c0];
            #pragma unroll
            for (int r = 0; r < 8; ++r) acc[r] += sg[r * 256 + j] * wv;
        }
        #pragma unroll
        for (int r = 0; r < 8; ++r) *(f32x4*)&sh.m.ps[jq][r][c0] = acc[r];
        __syncthreads();
        #pragma unroll
        for (int r = 0; r < 8; ++r)
            M[(r0 + r) * 256 + t] =
                sh.m.ps[0][r][t] + sh.m.ps[1][r][t] + sh.m.ps[2][r][t] + sh.m.ps[3][r][t];
    }
}

// ---------------------------------------------------------------------------
// Main (NO LDS, NO BARRIERS): grid 256 = 32 b x 8 ig; 512 thr = 8 waves =
// (mg 2) x (ng 4). Wave (mg,ng): rows [mg*32,+32), cols [ng*64,+64); 8 i's.
// All operands global: bfr (W2h slice, reg-resident), rh (Rh rows,
// reg-resident, ii-invariant), lhv (Lh row, 4 distinct 16B/wave, L1-hot).
// ii-loop NOT unrolled (unroll 1) so only 8 lhv loads are ever in flight —
// R7's full unroll caused catastrophic spill. launch_bounds(512,1) gives the
// allocator a 512-VGPR budget; demand ~250 -> 2 waves/SIMD, zero spill.
// ---------------------------------------------------------------------------
__global__ __launch_bounds__(512, 1) void rn_main(
    const _Float16* __restrict__ Lh, const _Float16* __restrict__ Rh,
    const _Float16* __restrict__ W2h, const float* __restrict__ gb2,
    float* __restrict__ S)
{
    const int blk = blockIdx.x;               // 256 = 32 b x 8 ig
    const int b = blk >> 3, ig = blk & 7;
    const int t = threadIdx.x, lane = t & 63, w = t >> 6;
    const int mg = w >> 2, ng = w & 3;
    const int lc = lane & 15, lg = lane >> 4;

    // register-resident B: 4 n-tiles x 8 ks (128 VGPR), from L2-hot W2h
    half8 bfr[4][8];
    #pragma unroll
    for (int n = 0; n < 4; ++n)
        #pragma unroll
        for (int ks = 0; ks < 8; ++ks)
            bfr[n][ks] = *(const half8*)(W2h + (ng * 64 + n * 16 + lc) * 256 + ks * 32 + lg * 8);

    // register-resident Rh rows: 2 m-tiles x 8 ks (64 VGPR), ii-invariant
    half8 rh[2][8];
    #pragma unroll
    for (int m2 = 0; m2 < 2; ++m2) {
        int row = b * 64 + mg * 32 + m2 * 16 + lc;
        #pragma unroll
        for (int ks = 0; ks < 8; ++ks)
            rh[m2][ks] = *(const half8*)(Rh + row * 256 + ks * 32 + lg * 8);
    }

    float bias[4];
    #pragma unroll
    for (int n = 0; n < 4; ++n) bias[n] = gb2[ng * 64 + n * 16 + lc];

    const _Float16* lbase = Lh + (b * 64 + ig * 8) * 256;
    const half8 zero8 = {(_Float16)0.f, (_Float16)0.f, (_Float16)0.f, (_Float16)0.f,
                         (_Float16)0.f, (_Float16)0.f, (_Float16)0.f, (_Float16)0.f};
    const f32x4 zero4 = (f32x4){0.f, 0.f, 0.f, 0.f};
    float csum[4] = {0.f, 0.f, 0.f, 0.f};

    #pragma unroll 1
    for (int ii = 0; ii < 8; ++ii) {
        f32x4 acc[2][4];
        #pragma unroll
        for (int m2 = 0; m2 < 2; ++m2)
            #pragma unroll
            for (int n = 0; n < 4; ++n)
                acc[m2][n] = zero4;

        #pragma unroll
        for (int ks = 0; ks < 8; ++ks) {
            half8 lhv = *(const half8*)(lbase + ii * 256 + ks * 32 + lg * 8);
            #pragma unroll
            for (int m2 = 0; m2 < 2; ++m2) {
                half8 av = __builtin_elementwise_max(lhv + rh[m2][ks], zero8);
                #pragma unroll
                for (int n = 0; n < 4; ++n)
                    acc[m2][n] = __builtin_amdgcn_mfma_f32_16x16x32_f16(
                        av, bfr[n][ks], acc[m2][n], 0, 0, 0);
            }
        }

        const int iglob = ig * 8 + ii;
        #pragma unroll
        for (int n = 0; n < 4; ++n) {
            #pragma unroll
            for (int m2 = 0; m2 < 2; ++m2) {
                #pragma unroll
                for (int q = 0; q < 4; ++q) {
                    int row = mg * 32 + m2 * 16 + lg * 4 + q;   // = j
                    float v = fmaxf(acc[m2][n][q] + bias[n], 0.f);
                    csum[n] += (row == iglob) ? 0.f : v;
                }
            }
        }
    }

    #pragma unroll
    for (int n = 0; n < 4; ++n) {
        float cs = csum[n];
        cs += __shfl_xor(cs, 16);
        cs += __shfl_xor(cs, 32);
        if (lane < 16) atomicAdd(&S[b * 256 + ng * 64 + n * 16 + lc], cs);
    }
}

// ---------------------------------------------------------------------------
// Final (2 phases): block per b, 1024 thr = (64 col-groups of 4) x (16 kq).
//   u   = relu(S[b] @ M + d);  out = u @ fW2 + fb2
// fW2 fragments prefetched into regs during phase A.
// ---------------------------------------------------------------------------
__global__ __launch_bounds__(1024) void rn_final(
    const float* __restrict__ S, const float* __restrict__ M,
    const float* __restrict__ dvec, const float* __restrict__ fW2,
    const float* __restrict__ fb2, float* __restrict__ out)
{
    __shared__ float vec[256];
    __shared__ float ps[16][260];
    const int b = blockIdx.x, t = threadIdx.x;
    const int cg = t & 63, kq = t >> 6;
    const int c0 = cg * 4;

    if (t < 256) vec[t] = S[b * 256 + t];
    __syncthreads();

    f32x4 w2r[16];
    {
        f32x4 s = (f32x4){0.f, 0.f, 0.f, 0.f};
        #pragma unroll
        for (int kk = 0; kk < 16; ++kk) {
            int k = kq * 16 + kk;
            s += (*(const f32x4*)&M[k * 256 + c0]) * vec[k];
        }
        *(f32x4*)&ps[kq][c0] = s;
        #pragma unroll
        for (int kk = 0; kk < 16; ++kk)
            w2r[kk] = *(const f32x4*)&fW2[(kq * 16 + kk) * 256 + c0];
    }
    __syncthreads();
    if (t < 256) {
        float a = 0.f;
        #pragma unroll
        for (int q = 0; q < 16; ++q) a += ps[q][t];
        vec[t] = fmaxf(a + dvec[t], 0.f);
    }
    __syncthreads();

    {
        f32x4 s = (f32x4){0.f, 0.f, 0.f, 0.f};
        #pragma unroll
        for (int kk = 0; kk < 16; ++kk)
            s += w2r[kk] * vec[kq * 16 + kk];
        *(f32x4*)&ps[kq][c0] = s;
    }
    __syncthreads();
    if (t < 256) {
        float a = 0.f;
        #pragma unroll
        for (int q = 0; q < 16; ++q) a += ps[q][t];
        out[b * 256 + t] = a + fb2[t];
    }
}

extern "C" void kernel_launch(void* const* d_in, const int* in_sizes, int n_in,
                              void* d_out, int out_size, void* d_ws, size_t ws_size,
                              hipStream_t stream)
{
    const float* obj = (const float*)d_in[0];
    const float* gW1 = (const float*)d_in[1];
    const float* gb1 = (const float*)d_in[2];
    const float* gW2 = (const float*)d_in[3];
    const float* gb2 = (const float*)d_in[4];
    const float* gW3 = (const float*)d_in[5];
    const float* gb3 = (const float*)d_in[6];
    const float* fW1 = (const float*)d_in[7];
    const float* fb1 = (const float*)d_in[8];
    const float* fW2 = (const float*)d_in[9];
    const float* fb2 = (const float*)d_in[10];
    float* out = (float*)d_out;

    char* ws = (char*)d_ws;
    _Float16* Lh  = (_Float16*)(ws);                           // 1 MB
    _Float16* Rh  = (_Float16*)(ws + (1u << 20));              // 1 MB (linear fp16)
    _Float16* W2h = (_Float16*)(ws + (2u << 20));              // 128 KB
    float*    S   = (float*)(ws + (2u << 20) + (128u << 10));  // 32 KB
    float*    M   = (float*)(ws + (2u << 20) + (160u << 10));  // 256 KB
    float*    dv  = (float*)(ws + (2u << 20) + (416u << 10));  // 1 KB

    rn_prep <<<305, 256, 0, stream>>>(obj, gW1, gb1, gW2, gW3, gb3, fW1, fb1,
                                      Lh, Rh, W2h, S, M, dv);
    rn_main <<<256, 512, 0, stream>>>(Lh, Rh, W2h, gb2, S);
    rn_final<<<32, 1024, 0, stream>>>(S, M, dv, fW2, fb2, out);
}

// Round 9
// 50.433 us; speedup vs baseline: 2.8248x; 1.0449x over previous
//
#include <hip/hip_runtime.h>
#include <hip/hip_bf16.h>

// B=32, N=64, D=128, H=256
typedef __attribute__((ext_vector_type(8))) _Float16 half8;
typedef __attribute__((ext_vector_type(4))) float f32x4;

// ---------------------------------------------------------------------------
// Prep: blocks 0..511  : L/R = objects @ gW1(top/bottom), 4 rows each.
//         Lh = fp16(L + gb1)  [row][k] linear (512B rows)
//         Rh = fp16(R)        rows of 512B, 16B-units XOR-swizzled:
//                             byte = row*512 + (2k ^ ((row&15)<<4))
//       blocks 512..527: transpose gW2 -> W2h[col][k] fp16
//       block  528     : dvec = 4032*(gb3@fW1) + fb1
//       blocks 529..560: M = gW3 @ fW1, 8 rows each (4-way j-split)
// LDS overlaid via union (40KB).
// ---------------------------------------------------------------------------
union PrepShared {
    struct { float so[4 * 128]; float tt[64 * 65]; } a;
    struct { float sg[8 * 256]; float ps[4][8][256]; } m;
};

__global__ __launch_bounds__(256) void rn_prep(
    const float* __restrict__ obj, const float* __restrict__ gW1,
    const float* __restrict__ gb1, const float* __restrict__ gW2,
    const float* __restrict__ gW3, const float* __restrict__ gb3,
    const float* __restrict__ fW1, const float* __restrict__ fb1,
    _Float16* __restrict__ Lh, char* __restrict__ RhB,
    _Float16* __restrict__ W2h, float* __restrict__ M, float* __restrict__ dvec)
{
    __shared__ PrepShared sh;
    const int blk = blockIdx.x, t = threadIdx.x;

    if (blk < 512) {
        float* so = sh.a.so;
        const int r0 = blk * 4;
        #pragma unroll
        for (int it = 0; it < 2; ++it) so[it * 256 + t] = obj[r0 * 128 + it * 256 + t];
        __syncthreads();
        float accL[4], accR[4];
        #pragma unroll
        for (int r = 0; r < 4; ++r) { accL[r] = 0.f; accR[r] = 0.f; }
        for (int k = 0; k < 128; ++k) {
            float wL = gW1[k * 256 + t];
            float wR = gW1[(128 + k) * 256 + t];
            #pragma unroll
            for (int r = 0; r < 4; ++r) {
                float o = so[r * 128 + k];
                accL[r] += o * wL;
                accR[r] += o * wR;
            }
        }
        float bb = gb1[t];
        #pragma unroll
        for (int r = 0; r < 4; ++r) {
            int row = r0 + r;
            Lh[row * 256 + t] = (_Float16)(accL[r] + bb);
            *(_Float16*)(RhB + row * 512 + ((2 * t) ^ ((row & 15) << 4))) = (_Float16)accR[r];
        }
    } else if (blk < 528) {
        float* tt = sh.a.tt;
        const int tb = blk - 512;
        const int k0 = (tb >> 2) * 64, c0 = (tb & 3) * 64;
        for (int it = 0; it < 16; ++it) {
            int idx = it * 256 + t, rr = idx >> 6, cc = idx & 63;
            tt[rr * 65 + cc] = gW2[(k0 + rr) * 256 + c0 + cc];
        }
        __syncthreads();
        for (int it = 0; it < 16; ++it) {
            int idx = it * 256 + t, cr = idx >> 6, kk = idx & 63;
            W2h[(c0 + cr) * 256 + (k0 + kk)] = (_Float16)tt[kk * 65 + cr];
        }
    } else if (blk == 528) {
        const int cg = t & 63, jq = t >> 6, c0 = cg * 4;
        f32x4 a = (f32x4){0.f, 0.f, 0.f, 0.f};
        #pragma unroll 8
        for (int jj = 0; jj < 64; ++jj) {
            int j = jq * 64 + jj;
            a += gb3[j] * (*(const f32x4*)&fW1[j * 256 + c0]);
        }
        *(f32x4*)&sh.m.ps[jq][0][c0] = a;
        __syncthreads();
        float s = sh.m.ps[0][0][t] + sh.m.ps[1][0][t] + sh.m.ps[2][0][t] + sh.m.ps[3][0][t];
        dvec[t] = 4032.0f * s + fb1[t];
    } else {
        float* sg = sh.m.sg;
        const int r0 = (blk - 529) * 8;
        const int cg = t & 63, jq = t >> 6, c0 = cg * 4;
        #pragma unroll
        for (int it = 0; it < 8; ++it) sg[it * 256 + t] = gW3[(r0 + it) * 256 + t];
        __syncthreads();
        f32x4 acc[8];
        #pragma unroll
        for (int r = 0; r < 8; ++r) acc[r] = (f32x4){0.f, 0.f, 0.f, 0.f};
        #pragma unroll 8
        for (int jj = 0; jj < 64; ++jj) {
            int j = jq * 64 + jj;
            f32x4 wv = *(const f32x4*)&fW1[j * 256 + c0];
            #pragma unroll
            for (int r = 0; r < 8; ++r) acc[r] += sg[r * 256 + j] * wv;
        }
        #pragma unroll
        for (int r = 0; r < 8; ++r) *(f32x4*)&sh.m.ps[jq][r][c0] = acc[r];
        __syncthreads();
        #pragma unroll
        for (int r = 0; r < 8; ++r)
            M[(r0 + r) * 256 + t] =
                sh.m.ps[0][r][t] + sh.m.ps[1][r][t] + sh.m.ps[2][r][t] + sh.m.ps[3][r][t];
    }
}

// ---------------------------------------------------------------------------
// Main (= R4 structure): grid 256 = 32 b x 8 ig; 512 thr = 8 waves =
// (mg 2) x (ng 4). Wave (mg,ng): rows [mg*32,+32), cols [ng*64,+64); 8 i's.
// W2 slice register-resident (bfr, 128 VGPR). Rh[b] (pre-swizzled) + Lh rows
// staged in LDS once; wave's Rh rows hoisted to regs (ii-invariant).
// A-frag: pk_max(pk_add(lh,rh),0); mfma_f32_16x16x32_f16. Column sums
// accumulated across 8 i's; partials STORED (no atomics) to
// Spart[((b*8+ig)*2+mg)*256 + col].
// ---------------------------------------------------------------------------
__global__ __launch_bounds__(512, 2) void rn_main(
    const char* __restrict__ LhB, const char* __restrict__ RhB,
    const _Float16* __restrict__ W2h, const float* __restrict__ gb2,
    float* __restrict__ Spart)
{
    __shared__ __attribute__((aligned(16))) char smem[36864];  // Rh 32KB + Lh 4KB
    const int blk = blockIdx.x;               // 256 = 32 b x 8 ig
    const int b = blk >> 3, ig = blk & 7;
    const int t = threadIdx.x, lane = t & 63, w = t >> 6;
    const int mg = w >> 2, ng = w & 3;
    const int lc = lane & 15, lg = lane >> 4;

    {   // stage Rh[b] (pre-swizzled, linear) + Lh rows ig*8..+8
        const char* gR = RhB + b * 32768;
        #pragma unroll
        for (int it = 0; it < 4; ++it) {
            int u = it * 512 + t;
            *(f32x4*)(smem + u * 16) = *(const f32x4*)(gR + u * 16);
        }
        if (t < 256) {
            const char* gL = LhB + (b * 64 + ig * 8) * 512;
            *(f32x4*)(smem + 32768 + t * 16) = *(const f32x4*)(gL + t * 16);
        }
    }

    // register-resident B (ii/mg-invariant): 4 n-tiles x 8 ks
    half8 bfr[4][8];
    #pragma unroll
    for (int n = 0; n < 4; ++n)
        #pragma unroll
        for (int ks = 0; ks < 8; ++ks)
            bfr[n][ks] = *(const half8*)(W2h + (ng * 64 + n * 16 + lc) * 256 + ks * 32 + lg * 8);

    float bias[4];
    #pragma unroll
    for (int n = 0; n < 4; ++n) bias[n] = gb2[ng * 64 + n * 16 + lc];

    __syncthreads();

    // hoist this wave's Rh rows into regs: 2 m-tiles x 8 ks (ii-invariant)
    half8 rh[2][8];
    #pragma unroll
    for (int m2 = 0; m2 < 2; ++m2) {
        int row = mg * 32 + m2 * 16 + lc;
        #pragma unroll
        for (int ks = 0; ks < 8; ++ks) {
            int kb = ks * 64 + lg * 16;
            rh[m2][ks] = *(const half8*)(smem + row * 512 + (kb ^ (lc << 4)));
        }
    }

    const half8 zero8 = {(_Float16)0.f, (_Float16)0.f, (_Float16)0.f, (_Float16)0.f,
                         (_Float16)0.f, (_Float16)0.f, (_Float16)0.f, (_Float16)0.f};
    float csum[4] = {0.f, 0.f, 0.f, 0.f};

    for (int ii = 0; ii < 8; ++ii) {
        f32x4 acc[2][4];
        #pragma unroll
        for (int m2 = 0; m2 < 2; ++m2)
            #pragma unroll
            for (int n = 0; n < 4; ++n)
                acc[m2][n] = (f32x4){0.f, 0.f, 0.f, 0.f};

        #pragma unroll
        for (int ks = 0; ks < 8; ++ks) {
            half8 lhv = *(const half8*)(smem + 32768 + ii * 512 + ks * 64 + lg * 16);
            #pragma unroll
            for (int m2 = 0; m2 < 2; ++m2) {
                half8 av = __builtin_elementwise_max(lhv + rh[m2][ks], zero8);
                #pragma unroll
                for (int n = 0; n < 4; ++n)
                    acc[m2][n] = __builtin_amdgcn_mfma_f32_16x16x32_f16(
                        av, bfr[n][ks], acc[m2][n], 0, 0, 0);
            }
        }

        const int iglob = ig * 8 + ii;
        #pragma unroll
        for (int n = 0; n < 4; ++n) {
            float cs = 0.f;
            #pragma unroll
            for (int m2 = 0; m2 < 2; ++m2)
                #pragma unroll
                for (int q = 0; q < 4; ++q) {
                    int row = mg * 32 + m2 * 16 + lg * 4 + q;   // = j
                    float v = fmaxf(acc[m2][n][q] + bias[n], 0.f);
                    cs += (row == iglob) ? 0.f : v;
                }
            csum[n] += cs;
        }
    }

    #pragma unroll
    for (int n = 0; n < 4; ++n) {
        float cs = csum[n];
        cs += __shfl_xor(cs, 16);
        cs += __shfl_xor(cs, 32);
        if (lane < 16)
            Spart[((b * 8 + ig) * 2 + mg) * 256 + ng * 64 + n * 16 + lc] = cs;
    }
}

// ---------------------------------------------------------------------------
// Final (2 phases): block per b, 1024 thr = (64 col-groups of 4) x (16 kq).
//   vec = sum of 16 partials; u = relu(vec @ M + d); out = u @ fW2 + fb2
// fW2 fragments prefetched into regs during phase A.
// ---------------------------------------------------------------------------
__global__ __launch_bounds__(1024) void rn_final(
    const float* __restrict__ Spart, const float* __restrict__ M,
    const float* __restrict__ dvec, const float* __restrict__ fW2,
    const float* __restrict__ fb2, float* __restrict__ out)
{
    __shared__ float vec[256];
    __shared__ float ps[16][260];
    const int b = blockIdx.x, t = threadIdx.x;
    const int cg = t & 63, kq = t >> 6;
    const int c0 = cg * 4;

    if (t < 256) {
        float a = 0.f;
        #pragma unroll
        for (int p = 0; p < 16; ++p) a += Spart[(b * 16 + p) * 256 + t];
        vec[t] = a;
    }
    __syncthreads();

    f32x4 w2r[16];
    {
        f32x4 s = (f32x4){0.f, 0.f, 0.f, 0.f};
        #pragma unroll
        for (int kk = 0; kk < 16; ++kk) {
            int k = kq * 16 + kk;
            s += (*(const f32x4*)&M[k * 256 + c0]) * vec[k];
        }
        *(f32x4*)&ps[kq][c0] = s;
        #pragma unroll
        for (int kk = 0; kk < 16; ++kk)
            w2r[kk] = *(const f32x4*)&fW2[(kq * 16 + kk) * 256 + c0];
    }
    __syncthreads();
    if (t < 256) {
        float a = 0.f;
        #pragma unroll
        for (int q = 0; q < 16; ++q) a += ps[q][t];
        vec[t] = fmaxf(a + dvec[t], 0.f);
    }
    __syncthreads();

    {
        f32x4 s = (f32x4){0.f, 0.f, 0.f, 0.f};
        #pragma unroll
        for (int kk = 0; kk < 16; ++kk)
            s += w2r[kk] * vec[kq * 16 + kk];
        *(f32x4*)&ps[kq][c0] = s;
    }
    __syncthreads();
    if (t < 256) {
        float a = 0.f;
        #pragma unroll
        for (int q = 0; q < 16; ++q) a += ps[q][t];
        out[b * 256 + t] = a + fb2[t];
    }
}

extern "C" void kernel_launch(void* const* d_in, const int* in_sizes, int n_in,
                              void* d_out, int out_size, void* d_ws, size_t ws_size,
                              hipStream_t stream)
{
    const float* obj = (const float*)d_in[0];
    const float* gW1 = (const float*)d_in[1];
    const float* gb1 = (const float*)d_in[2];
    const float* gW2 = (const float*)d_in[3];
    const float* gb2 = (const float*)d_in[4];
    const float* gW3 = (const float*)d_in[5];
    const float* gb3 = (const float*)d_in[6];
    const float* fW1 = (const float*)d_in[7];
    const float* fb1 = (const float*)d_in[8];
    const float* fW2 = (const float*)d_in[9];
    const float* fb2 = (const float*)d_in[10];
    float* out = (float*)d_out;

    char* ws = (char*)d_ws;
    _Float16* Lh    = (_Float16*)(ws);                           // 1 MB
    char*     RhB   = ws + (1u << 20);                           // 1 MB (swizzled fp16)
    _Float16* W2h   = (_Float16*)(ws + (2u << 20));              // 128 KB
    float*    Spart = (float*)(ws + (2u << 20) + (128u << 10));  // 512 KB
    float*    M     = (float*)(ws + (2u << 20) + (640u << 10));  // 256 KB
    float*    dv    = (float*)(ws + (2u << 20) + (896u << 10));  // 1 KB

    rn_prep <<<561, 256, 0, stream>>>(obj, gW1, gb1, gW2, gW3, gb3, fW1, fb1,
                                      Lh, RhB, W2h, M, dv);
    rn_main <<<256, 512, 0, stream>>>((const char*)Lh, RhB, W2h, gb2, Spart);
    rn_final<<<32, 1024, 0, stream>>>(Spart, M, dv, fW2, fb2, out);
}